// Round 1
// baseline (2383.801 us; speedup 1.0000x reference)
//
#include <hip/hip_runtime.h>
#include <math.h>

#define NN 4096
#define FF 256
#define RR 8
#define BQ 16384

// ---------------------------------------------------------------------------
// Kernel 1: AH[r] = A[r] @ H     (M=4096 rows, K=4096, N=256 cols), batched r
// grid (FF/128=2, NN/128=32, RR=8), block 256, 8x8 outputs per thread.
// ---------------------------------------------------------------------------
__global__ __launch_bounds__(256) void gemm_ah(const float* __restrict__ A,
                                               const float* __restrict__ H,
                                               float* __restrict__ AH) {
    __shared__ float As[16][132];   // [k][row], +4 pad (132 floats = 16B-aligned rows)
    __shared__ float Bs[16][128];   // [k][col]

    const int tid = threadIdx.x;
    const int r   = blockIdx.z;
    const int n0  = blockIdx.y * 128;
    const int f0  = blockIdx.x * 128;

    const float* __restrict__ Ar = A + (size_t)r * NN * NN;

    const int tx = tid & 15;   // col group (8 cols)
    const int ty = tid >> 4;   // row group (8 rows)

    // A-tile load mapping: 128 rows x 16 k; thread loads 8 floats of one row
    const int lar = tid >> 1;          // row 0..127
    const int lac = (tid & 1) * 8;     // k offset 0 or 8
    // B-tile load mapping: 16 k-rows x 128 cols; thread loads 2 float4
    const int lbr = tid >> 5;          // k-row 0..7 (and +8)
    const int lbc = (tid & 31) * 4;    // col 0..124

    float acc[8][8];
#pragma unroll
    for (int i = 0; i < 8; ++i)
#pragma unroll
        for (int j = 0; j < 8; ++j) acc[i][j] = 0.0f;

    const size_t arow = (size_t)(n0 + lar) * NN;

    for (int kb = 0; kb < NN; kb += 16) {
        float4 a0 = *(const float4*)&Ar[arow + kb + lac];
        float4 a1 = *(const float4*)&Ar[arow + kb + lac + 4];
        float4 b0 = *(const float4*)&H[(size_t)(kb + lbr) * FF + f0 + lbc];
        float4 b1 = *(const float4*)&H[(size_t)(kb + lbr + 8) * FF + f0 + lbc];

        __syncthreads();   // previous tile's compute done before overwrite
        As[lac + 0][lar] = a0.x;
        As[lac + 1][lar] = a0.y;
        As[lac + 2][lar] = a0.z;
        As[lac + 3][lar] = a0.w;
        As[lac + 4][lar] = a1.x;
        As[lac + 5][lar] = a1.y;
        As[lac + 6][lar] = a1.z;
        As[lac + 7][lar] = a1.w;
        *(float4*)&Bs[lbr][lbc]     = b0;
        *(float4*)&Bs[lbr + 8][lbc] = b1;
        __syncthreads();

#pragma unroll
        for (int k = 0; k < 16; ++k) {
            float4 aA = *(const float4*)&As[k][ty * 8];
            float4 aB = *(const float4*)&As[k][ty * 8 + 4];
            float4 bA = *(const float4*)&Bs[k][tx * 8];
            float4 bB = *(const float4*)&Bs[k][tx * 8 + 4];
            float a[8] = {aA.x, aA.y, aA.z, aA.w, aB.x, aB.y, aB.z, aB.w};
            float b[8] = {bA.x, bA.y, bA.z, bA.w, bB.x, bB.y, bB.z, bB.w};
#pragma unroll
            for (int i = 0; i < 8; ++i)
#pragma unroll
                for (int j = 0; j < 8; ++j) acc[i][j] += a[i] * b[j];
        }
    }

    float* __restrict__ outp = AH + ((size_t)r * NN + n0) * FF + f0;
#pragma unroll
    for (int i = 0; i < 8; ++i) {
        const size_t row = (size_t)(ty * 8 + i) * FF;
        float4 v0 = {acc[i][0], acc[i][1], acc[i][2], acc[i][3]};
        float4 v1 = {acc[i][4], acc[i][5], acc[i][6], acc[i][7]};
        *(float4*)&outp[row + tx * 8]     = v0;
        *(float4*)&outp[row + tx * 8 + 4] = v1;
    }
}

// ---------------------------------------------------------------------------
// Kernel 2: Hout[n,o] = sum_r c[r,n] * sum_f AH[r,n,f] * W[r,o,f]
// Treated as GEMM  M=4096(n) x N=256(o) x K=2048(r*F+f), c folded on A load.
// grid (FF/64=4, NN/64=64), block 256, 4x4 per thread, BK=32.
// ---------------------------------------------------------------------------
__global__ __launch_bounds__(256) void combine(const float* __restrict__ AH,
                                               const float* __restrict__ c,
                                               const float* __restrict__ W,
                                               float* __restrict__ Hout) {
    __shared__ float As[32][68];   // [k][n-row], pad to 68 (16B-aligned rows)
    __shared__ float Ws[32][68];   // [k][o-row]

    const int tid = threadIdx.x;
    const int o0  = blockIdx.x * 64;
    const int n0  = blockIdx.y * 64;
    const int tx  = tid & 15;
    const int ty  = tid >> 4;

    const int lr = tid >> 2;        // row 0..63
    const int lc = (tid & 3) * 8;   // k offset 0,8,16,24

    float acc[4][4];
#pragma unroll
    for (int i = 0; i < 4; ++i)
#pragma unroll
        for (int j = 0; j < 4; ++j) acc[i][j] = 0.0f;

    for (int kb = 0; kb < RR * FF; kb += 32) {
        const int r  = kb >> 8;        // 256 | kb chunk -> r fixed per tile
        const int fo = kb & 255;
        const float cv = c[r * NN + n0 + lr];
        float4 a0 = *(const float4*)&AH[((size_t)r * NN + n0 + lr) * FF + fo + lc];
        float4 a1 = *(const float4*)&AH[((size_t)r * NN + n0 + lr) * FF + fo + lc + 4];
        float4 w0 = *(const float4*)&W[((size_t)r * FF + o0 + lr) * FF + fo + lc];
        float4 w1 = *(const float4*)&W[((size_t)r * FF + o0 + lr) * FF + fo + lc + 4];

        __syncthreads();
        As[lc + 0][lr] = cv * a0.x;
        As[lc + 1][lr] = cv * a0.y;
        As[lc + 2][lr] = cv * a0.z;
        As[lc + 3][lr] = cv * a0.w;
        As[lc + 4][lr] = cv * a1.x;
        As[lc + 5][lr] = cv * a1.y;
        As[lc + 6][lr] = cv * a1.z;
        As[lc + 7][lr] = cv * a1.w;
        Ws[lc + 0][lr] = w0.x;
        Ws[lc + 1][lr] = w0.y;
        Ws[lc + 2][lr] = w0.z;
        Ws[lc + 3][lr] = w0.w;
        Ws[lc + 4][lr] = w1.x;
        Ws[lc + 5][lr] = w1.y;
        Ws[lc + 6][lr] = w1.z;
        Ws[lc + 7][lr] = w1.w;
        __syncthreads();

#pragma unroll
        for (int k = 0; k < 32; ++k) {
            float4 av = *(const float4*)&As[k][ty * 4];
            float4 wv = *(const float4*)&Ws[k][tx * 4];
            float a[4] = {av.x, av.y, av.z, av.w};
            float w[4] = {wv.x, wv.y, wv.z, wv.w};
#pragma unroll
            for (int i = 0; i < 4; ++i)
#pragma unroll
                for (int j = 0; j < 4; ++j) acc[i][j] += a[i] * w[j];
        }
    }

#pragma unroll
    for (int i = 0; i < 4; ++i) {
        float4 v = {acc[i][0], acc[i][1], acc[i][2], acc[i][3]};
        *(float4*)&Hout[(size_t)(n0 + ty * 4 + i) * FF + o0 + tx * 4] = v;
    }
}

// ---------------------------------------------------------------------------
// Kernel 3: score[b] = sigmoid( sum_f E1[b,f] * Mdiag[rel[b],f] * E2[b,f] )
// rel_mats are exactly diagonal (off-diag entries are 0.0f => contribute
// exactly 0 to the fp32 sum), so diagonal-only is numerically identical.
// One wave per b; lane handles one float4 (4 features); shuffle reduce.
// ---------------------------------------------------------------------------
__global__ __launch_bounds__(256) void score_k(const float* __restrict__ H2,
                                               const float* __restrict__ relm,
                                               const int* __restrict__ e1,
                                               const int* __restrict__ rel,
                                               const int* __restrict__ e2,
                                               float* __restrict__ out) {
    const int wave = threadIdx.x >> 6;
    const int lane = threadIdx.x & 63;
    const int b = blockIdx.x * 4 + wave;
    if (b >= BQ) return;

    const int rr = rel[b];
    const float4* __restrict__ x = (const float4*)(H2 + (size_t)e1[b] * FF);
    const float4* __restrict__ y = (const float4*)(H2 + (size_t)e2[b] * FF);
    const float* __restrict__ M = relm + (size_t)rr * FF * FF;

    float4 xv = x[lane];
    float4 yv = y[lane];
    const int f = lane * 4;
    float s = xv.x * yv.x * M[(size_t)(f + 0) * (FF + 1)]
            + xv.y * yv.y * M[(size_t)(f + 1) * (FF + 1)]
            + xv.z * yv.z * M[(size_t)(f + 2) * (FF + 1)]
            + xv.w * yv.w * M[(size_t)(f + 3) * (FF + 1)];

#pragma unroll
    for (int off = 32; off > 0; off >>= 1) s += __shfl_down(s, off, 64);

    if (lane == 0) out[b] = 1.0f / (1.0f + expf(-s));
}

// ---------------------------------------------------------------------------
extern "C" void kernel_launch(void* const* d_in, const int* in_sizes, int n_in,
                              void* d_out, int out_size, void* d_ws, size_t ws_size,
                              hipStream_t stream) {
    const float* A    = (const float*)d_in[0];   // [R,N,N]
    const float* feat = (const float*)d_in[1];   // [N,F]
    const float* c    = (const float*)d_in[2];   // [R,N,1]
    const float* W1   = (const float*)d_in[3];   // [R,F,F]
    const float* W2   = (const float*)d_in[4];   // [R,F,F]
    const float* relm = (const float*)d_in[5];   // [R,F,F]
    const int*   e1   = (const int*)d_in[6];     // [B]
    const int*   rel  = (const int*)d_in[7];     // [B]
    const int*   e2   = (const int*)d_in[8];     // [B]
    float* out = (float*)d_out;                  // [B]

    float* AH = (float*)d_ws;                        // R*N*F = 32 MB
    float* H1 = AH + (size_t)RR * NN * FF;           // N*F   =  4 MB
    float* H2 = H1 + (size_t)NN * FF;                // N*F   =  4 MB

    dim3 g1(FF / 128, NN / 128, RR);   // (2, 32, 8)
    dim3 g2(FF / 64, NN / 64);         // (4, 64)

    // Layer 1
    gemm_ah<<<g1, 256, 0, stream>>>(A, feat, AH);
    combine<<<g2, 256, 0, stream>>>(AH, c, W1, H1);
    // Layer 2
    gemm_ah<<<g1, 256, 0, stream>>>(A, H1, AH);
    combine<<<g2, 256, 0, stream>>>(AH, c, W2, H2);
    // Scoring
    score_k<<<BQ / 4, 256, 0, stream>>>(H2, relm, e1, rel, e2, out);
}

// Round 2
// 2365.344 us; speedup vs baseline: 1.0078x; 1.0078x over previous
//
#include <hip/hip_runtime.h>
#include <math.h>

#define NN 4096
#define FF 256
#define RR 8
#define BQ 16384

// ---------------------------------------------------------------------------
// Kernel 1: G[r] = H @ W[r]^T   (M=4096 nodes, N=256 out-feat, K=256 in-feat)
// grid (FF/64=4, NN/64=64, RR=8) = 2048 blocks; 64x64 tile, 4x4/thread, BK=32.
// ---------------------------------------------------------------------------
__global__ __launch_bounds__(256) void gemm_g(const float* __restrict__ H,
                                              const float* __restrict__ W,
                                              float* __restrict__ G) {
    __shared__ float Hs[32][68];   // [k][m-row], pad to 68
    __shared__ float Ws[32][68];   // [k][o-row]

    const int tid = threadIdx.x;
    const int r   = blockIdx.z;
    const int o0  = blockIdx.x * 64;
    const int m0  = blockIdx.y * 64;
    const int tx  = tid & 15;
    const int ty  = tid >> 4;

    const float* __restrict__ Wr = W + (size_t)r * FF * FF;

    const int lr = tid >> 2;        // row 0..63
    const int lc = (tid & 3) * 8;   // k offset 0,8,16,24

    float acc[4][4];
#pragma unroll
    for (int i = 0; i < 4; ++i)
#pragma unroll
        for (int j = 0; j < 4; ++j) acc[i][j] = 0.0f;

    for (int fb = 0; fb < FF; fb += 32) {
        float4 h0 = *(const float4*)&H[(size_t)(m0 + lr) * FF + fb + lc];
        float4 h1 = *(const float4*)&H[(size_t)(m0 + lr) * FF + fb + lc + 4];
        float4 w0 = *(const float4*)&Wr[(size_t)(o0 + lr) * FF + fb + lc];
        float4 w1 = *(const float4*)&Wr[(size_t)(o0 + lr) * FF + fb + lc + 4];

        __syncthreads();
        Hs[lc + 0][lr] = h0.x;  Hs[lc + 1][lr] = h0.y;
        Hs[lc + 2][lr] = h0.z;  Hs[lc + 3][lr] = h0.w;
        Hs[lc + 4][lr] = h1.x;  Hs[lc + 5][lr] = h1.y;
        Hs[lc + 6][lr] = h1.z;  Hs[lc + 7][lr] = h1.w;
        Ws[lc + 0][lr] = w0.x;  Ws[lc + 1][lr] = w0.y;
        Ws[lc + 2][lr] = w0.z;  Ws[lc + 3][lr] = w0.w;
        Ws[lc + 4][lr] = w1.x;  Ws[lc + 5][lr] = w1.y;
        Ws[lc + 6][lr] = w1.z;  Ws[lc + 7][lr] = w1.w;
        __syncthreads();

#pragma unroll
        for (int k = 0; k < 32; ++k) {
            float4 hv = *(const float4*)&Hs[k][ty * 4];
            float4 wv = *(const float4*)&Ws[k][tx * 4];
            float a[4] = {hv.x, hv.y, hv.z, hv.w};
            float b[4] = {wv.x, wv.y, wv.z, wv.w};
#pragma unroll
            for (int i = 0; i < 4; ++i)
#pragma unroll
                for (int j = 0; j < 4; ++j) acc[i][j] += a[i] * b[j];
        }
    }

    float* __restrict__ Gp = G + ((size_t)r * NN + m0) * FF + o0;
#pragma unroll
    for (int i = 0; i < 4; ++i) {
        float4 v = {acc[i][0], acc[i][1], acc[i][2], acc[i][3]};
        *(float4*)&Gp[(size_t)(ty * 4 + i) * FF + tx * 4] = v;
    }
}

// ---------------------------------------------------------------------------
// Kernel 2: P[r] = c[r] * (A[r] @ G[r])   (M=4096, K=4096, N=256), batched r
// grid (FF/128=2, NN/128=32, RR=8) = 512 blocks; 128x128 tile, 8x8/thread,
// BK=16, split fragments (tx*4 | 64+tx*4) => conflict-free LDS reads,
// register prefetch of next K-tile overlapping compute.
// ---------------------------------------------------------------------------
__global__ __launch_bounds__(256) void gemm_ag(const float* __restrict__ A,
                                               const float* __restrict__ G,
                                               const float* __restrict__ c,
                                               float* __restrict__ P) {
    __shared__ float As[16][132];   // [k][row], +4 pad
    __shared__ float Bs[16][128];   // [k][col]

    const int tid = threadIdx.x;
    const int r   = blockIdx.z;
    const int n0  = blockIdx.y * 128;
    const int f0  = blockIdx.x * 128;

    const float* __restrict__ Ar = A + (size_t)r * NN * NN;
    const float* __restrict__ Gr = G + (size_t)r * NN * FF;

    const int tx = tid & 15;   // col group
    const int ty = tid >> 4;   // row group (0..15)

    const int lar = tid >> 1;          // A row 0..127
    const int lac = (tid & 1) * 8;     // A k offset 0 or 8
    const int lbr = tid >> 5;          // B k-row 0..7 (and +8)
    const int lbc = (tid & 31) * 4;    // B col 0..124

    float acc[8][8];
#pragma unroll
    for (int i = 0; i < 8; ++i)
#pragma unroll
        for (int j = 0; j < 8; ++j) acc[i][j] = 0.0f;

    const size_t arow = (size_t)(n0 + lar) * NN;

    // prefetch tile 0
    float4 pa0 = *(const float4*)&Ar[arow + lac];
    float4 pa1 = *(const float4*)&Ar[arow + lac + 4];
    float4 pb0 = *(const float4*)&Gr[(size_t)lbr * FF + f0 + lbc];
    float4 pb1 = *(const float4*)&Gr[(size_t)(lbr + 8) * FF + f0 + lbc];

    for (int kb = 0; kb < NN; kb += 16) {
        __syncthreads();
        As[lac + 0][lar] = pa0.x;  As[lac + 1][lar] = pa0.y;
        As[lac + 2][lar] = pa0.z;  As[lac + 3][lar] = pa0.w;
        As[lac + 4][lar] = pa1.x;  As[lac + 5][lar] = pa1.y;
        As[lac + 6][lar] = pa1.z;  As[lac + 7][lar] = pa1.w;
        *(float4*)&Bs[lbr][lbc]     = pb0;
        *(float4*)&Bs[lbr + 8][lbc] = pb1;
        __syncthreads();

        if (kb + 16 < NN) {   // prefetch next tile while computing this one
            pa0 = *(const float4*)&Ar[arow + kb + 16 + lac];
            pa1 = *(const float4*)&Ar[arow + kb + 16 + lac + 4];
            pb0 = *(const float4*)&Gr[(size_t)(kb + 16 + lbr) * FF + f0 + lbc];
            pb1 = *(const float4*)&Gr[(size_t)(kb + 16 + lbr + 8) * FF + f0 + lbc];
        }

#pragma unroll
        for (int k = 0; k < 16; ++k) {
            float4 a0 = *(const float4*)&As[k][ty * 4];
            float4 a1 = *(const float4*)&As[k][64 + ty * 4];
            float4 b0 = *(const float4*)&Bs[k][tx * 4];
            float4 b1 = *(const float4*)&Bs[k][64 + tx * 4];
            float a[8] = {a0.x, a0.y, a0.z, a0.w, a1.x, a1.y, a1.z, a1.w};
            float b[8] = {b0.x, b0.y, b0.z, b0.w, b1.x, b1.y, b1.z, b1.w};
#pragma unroll
            for (int i = 0; i < 8; ++i)
#pragma unroll
                for (int j = 0; j < 8; ++j) acc[i][j] += a[i] * b[j];
        }
    }

    // epilogue: scale rows by c[r, n] and store the per-r plane
    float* __restrict__ Pp = P + ((size_t)r * NN + n0) * FF + f0;
#pragma unroll
    for (int i = 0; i < 8; ++i) {
        const int row = (i < 4) ? (ty * 4 + i) : (64 + ty * 4 + (i - 4));
        const float cv = c[r * NN + n0 + row];
        float4 v0 = {acc[i][0] * cv, acc[i][1] * cv, acc[i][2] * cv, acc[i][3] * cv};
        float4 v1 = {acc[i][4] * cv, acc[i][5] * cv, acc[i][6] * cv, acc[i][7] * cv};
        *(float4*)&Pp[(size_t)row * FF + tx * 4]      = v0;
        *(float4*)&Pp[(size_t)row * FF + 64 + tx * 4] = v1;
    }
}

// ---------------------------------------------------------------------------
// Kernel 3: Hout = sum_r P[r]   (elementwise over [N,F], float4 per thread)
// ---------------------------------------------------------------------------
__global__ __launch_bounds__(256) void reduce_p(const float* __restrict__ P,
                                                float* __restrict__ Hout) {
    const size_t idx = ((size_t)blockIdx.x * 256 + threadIdx.x) * 4;
    float4 s = *(const float4*)&P[idx];
#pragma unroll
    for (int r = 1; r < RR; ++r) {
        float4 v = *(const float4*)&P[(size_t)r * NN * FF + idx];
        s.x += v.x; s.y += v.y; s.z += v.z; s.w += v.w;
    }
    *(float4*)&Hout[idx] = s;
}

// ---------------------------------------------------------------------------
// Kernel 4: score[b] = sigmoid( sum_f E1[b,f] * Mdiag[rel[b],f] * E2[b,f] )
// rel_mats are exactly diagonal => diagonal-only is numerically identical.
// ---------------------------------------------------------------------------
__global__ __launch_bounds__(256) void score_k(const float* __restrict__ H2,
                                               const float* __restrict__ relm,
                                               const int* __restrict__ e1,
                                               const int* __restrict__ rel,
                                               const int* __restrict__ e2,
                                               float* __restrict__ out) {
    const int wave = threadIdx.x >> 6;
    const int lane = threadIdx.x & 63;
    const int b = blockIdx.x * 4 + wave;
    if (b >= BQ) return;

    const int rr = rel[b];
    const float4* __restrict__ x = (const float4*)(H2 + (size_t)e1[b] * FF);
    const float4* __restrict__ y = (const float4*)(H2 + (size_t)e2[b] * FF);
    const float* __restrict__ M = relm + (size_t)rr * FF * FF;

    float4 xv = x[lane];
    float4 yv = y[lane];
    const int f = lane * 4;
    float s = xv.x * yv.x * M[(size_t)(f + 0) * (FF + 1)]
            + xv.y * yv.y * M[(size_t)(f + 1) * (FF + 1)]
            + xv.z * yv.z * M[(size_t)(f + 2) * (FF + 1)]
            + xv.w * yv.w * M[(size_t)(f + 3) * (FF + 1)];

#pragma unroll
    for (int off = 32; off > 0; off >>= 1) s += __shfl_down(s, off, 64);

    if (lane == 0) out[b] = 1.0f / (1.0f + expf(-s));
}

// ---------------------------------------------------------------------------
extern "C" void kernel_launch(void* const* d_in, const int* in_sizes, int n_in,
                              void* d_out, int out_size, void* d_ws, size_t ws_size,
                              hipStream_t stream) {
    const float* A    = (const float*)d_in[0];   // [R,N,N]
    const float* feat = (const float*)d_in[1];   // [N,F]
    const float* c    = (const float*)d_in[2];   // [R,N,1]
    const float* W1   = (const float*)d_in[3];   // [R,F,F]
    const float* W2   = (const float*)d_in[4];   // [R,F,F]
    const float* relm = (const float*)d_in[5];   // [R,F,F]
    const int*   e1   = (const int*)d_in[6];     // [B]
    const int*   rel  = (const int*)d_in[7];     // [B]
    const int*   e2   = (const int*)d_in[8];     // [B]
    float* out = (float*)d_out;                  // [B]

    float* G  = (float*)d_ws;                    // R*N*F = 32 MB
    float* P  = G + (size_t)RR * NN * FF;        // R*N*F = 32 MB
    float* H1 = P + (size_t)RR * NN * FF;        // N*F   =  4 MB
    float* H2 = H1 + (size_t)NN * FF;            // N*F   =  4 MB

    dim3 gg(FF / 64, NN / 64, RR);     // (4, 64, 8) = 2048
    dim3 ga(FF / 128, NN / 128, RR);   // (2, 32, 8) = 512
    const int gr = (NN * FF / 4) / 256;  // 1024 blocks

    // Layer 1:  G = feat @ W1^T ;  P[r] = c[r]*(A[r]@G[r]) ;  H1 = sum_r P[r]
    gemm_g <<<gg, 256, 0, stream>>>(feat, W1, G);
    gemm_ag<<<ga, 256, 0, stream>>>(A, G, c, P);
    reduce_p<<<gr, 256, 0, stream>>>(P, H1);
    // Layer 2
    gemm_g <<<gg, 256, 0, stream>>>(H1, W2, G);
    gemm_ag<<<ga, 256, 0, stream>>>(A, G, c, P);
    reduce_p<<<gr, 256, 0, stream>>>(P, H2);
    // Scoring
    score_k<<<BQ / 4, 256, 0, stream>>>(H2, relm, e1, rel, e2, out);
}